// Round 2
// baseline (14481.699 us; speedup 1.0000x reference)
//
#include <hip/hip_runtime.h>
#include <hip/hip_bf16.h>
#include <math.h>

// ---------------------------------------------------------------------------
// Bi-LSTM encoder (final states only) -> 2-layer AR decoder (64 steps) -> vocab-3.
//   init_k      : zero decoder input buffer / flags (ws not re-poisoned between replays)
//   convert_k   : x, ew_ih_{f,b} -> bf16; bias sums
//   convert_w_k : W_hh (enc) and [W_ih|W_hh] (dec) -> packed f16 pairs
//   xproj_gemm  : bf16 MFMA GEMM -> Xproj[dir][t][b][1024] fp32 (+bias), dir1 reversed
//   encoder_k   : SELF-CONTAINED blocks (dir x batchrow), f16 dot2, zero cross-block sync
//   decoder_k   : persistent (L,bg,jg) blocks, f16 dot2, relaxed-atomic flag sync
//   logits_k    : h1 history @ lw^T + lb
// ---------------------------------------------------------------------------

typedef unsigned short u16;
typedef unsigned int u32;
typedef _Float16 f16;
typedef __bf16 bf16x8v __attribute__((ext_vector_type(8)));
typedef u16 u16x8 __attribute__((ext_vector_type(8)));
typedef u32 u32x4 __attribute__((ext_vector_type(4)));
typedef f16 f16x2 __attribute__((ext_vector_type(2)));
typedef float f32x4 __attribute__((ext_vector_type(4)));

__device__ __forceinline__ u16 f2bf(float f) {
  unsigned u = __builtin_bit_cast(unsigned, f);
  u += 0x7fffu + ((u >> 16) & 1u);
  return (u16)(u >> 16);
}

__device__ __forceinline__ u32 packf16(float a, float b) {
  u32 lo = (u32)__builtin_bit_cast(unsigned short, (f16)a);
  u32 hi = (u32)__builtin_bit_cast(unsigned short, (f16)b);
  return lo | (hi << 16);
}

__device__ __forceinline__ float dot2(u32 h, u32 w, float c) {
  return __builtin_amdgcn_fdot2(__builtin_bit_cast(f16x2, h),
                                __builtin_bit_cast(f16x2, w), c, false);
}

// ---------------------------------------------------------------------------
__global__ __launch_bounds__(256) void init_k(float* inpb, int* df) {
  int gid = blockIdx.x * 256 + threadIdx.x;   // grid 256*256 = 65536
  inpb[gid] = 0.f;
  if (gid < 256) df[gid] = 0;
}

// ---------------------------------------------------------------------------
__global__ __launch_bounds__(256) void convert_k(
    const float* __restrict__ x,
    const float* __restrict__ wfm, const float* __restrict__ wbm,
    const float* __restrict__ bif, const float* __restrict__ bhf,
    const float* __restrict__ bib, const float* __restrict__ bhb,
    const float* __restrict__ dbi0, const float* __restrict__ dbh0,
    const float* __restrict__ dbi1, const float* __restrict__ dbh1,
    u16* __restrict__ xbf, u16* __restrict__ wbf,
    float* __restrict__ bias2, float* __restrict__ dbias) {
  const long NX = 67108864L, NW = 1048576L;
  long gid = (long)blockIdx.x * 256 + threadIdx.x;
  if (gid < 1024) {
    bias2[gid]        = bif[gid] + bhf[gid];
    bias2[1024 + gid] = bib[gid] + bhb[gid];
    dbias[gid]        = dbi0[gid] + dbh0[gid];
    dbias[1024 + gid] = dbi1[gid] + dbh1[gid];
  }
  long total4 = (NX + 2 * NW) >> 2;
  long stride = (long)gridDim.x * 256;
  for (long q = gid; q < total4; q += stride) {
    long i = q << 2;
    const float* src; u16* dst; long o;
    if (i < NX)            { src = x;   dst = xbf;      o = i; }
    else if (i < NX + NW)  { src = wfm; dst = wbf;      o = i - NX; }
    else                   { src = wbm; dst = wbf + NW; o = i - NX - NW; }
    float4 v = *(const float4*)&src[o];
    dst[o + 0] = f2bf(v.x); dst[o + 1] = f2bf(v.y);
    dst[o + 2] = f2bf(v.z); dst[o + 3] = f2bf(v.w);
  }
}

// ---------------------------------------------------------------------------
// Weight repack to packed-f16 pairs.
//  enc: wf16t[d][kp<128][c<1024] = pack(whh_d[c][2kp], whh_d[c][2kp+1])
//  dec: dwf16[L][ks<16][kp<16][g<4][c<256], K=512 = [wih|whh]
__global__ __launch_bounds__(256) void convert_w_k(
    const float* __restrict__ whf, const float* __restrict__ whb,
    const float* __restrict__ wi0, const float* __restrict__ wh0,
    const float* __restrict__ wi1, const float* __restrict__ wh1,
    u32* __restrict__ wf16t, u32* __restrict__ dwf16) {
  int gid = blockIdx.x * 256 + threadIdx.x;   // grid 3072*256 = 786432
  if (gid < 262144) {
    int d = gid >> 17, kp = (gid >> 10) & 127, c = gid & 1023;
    const float* w = d ? whb : whf;
    wf16t[gid] = packf16(w[c * 256 + 2 * kp], w[c * 256 + 2 * kp + 1]);
  } else {
    int i = gid - 262144;                     // [L][ks][kp][g][c]
    int L = i >> 18, ks = (i >> 14) & 15, kp = (i >> 10) & 15;
    int g = (i >> 8) & 3, c = i & 255;
    int grow = g * 256 + c;
    int kk = (ks * 16 + kp) * 2;
    const float* wi = L ? wi1 : wi0;
    const float* wh = L ? wh1 : wh0;
    const float* s = (kk < 256) ? &wi[grow * 256 + kk] : &wh[grow * 256 + kk - 256];
    dwf16[i] = packf16(s[0], s[1]);
  }
}

// ---------------------------------------------------------------------------
// Xproj GEMM (unchanged from R1): C = Xbf @ Wbf^T + bias, 128x128 tiles.
__global__ __launch_bounds__(256) void xproj_gemm(
    const u16* __restrict__ xbf, const u16* __restrict__ wbf,
    const float* __restrict__ bias2, float* __restrict__ xp) {
  __shared__ u16 Al[128][40];
  __shared__ u16 Bl[128][40];
  int bid = blockIdx.x;
  int dir = bid >> 12, rem = bid & 4095, tb = rem >> 3, nb = rem & 7;
  int tsrc = dir ? (511 - tb) : tb;
  const u16* A  = xbf + (long)tsrc * (128 * 1024);
  const u16* Bw = wbf + (long)dir * (1024 * 1024) + (long)nb * (128 * 1024);
  float* C = xp + ((long)(dir * 512 + tb) * 128) * 1024 + nb * 128;
  const float* bias = bias2 + dir * 1024 + nb * 128;

  int tid = threadIdx.x, lane = tid & 63, wid = tid >> 6;
  int wr = wid >> 1, wc = wid & 1;
  int srow = tid >> 1, scol = (tid & 1) * 16;
  int fr = lane & 15, ko = lane >> 4;

  f32x4 acc[4][4] = {};
  for (int k0 = 0; k0 < 1024; k0 += 32) {
    u16x8 a0 = *(const u16x8*)&A[(long)srow * 1024 + k0 + scol];
    u16x8 a1 = *(const u16x8*)&A[(long)srow * 1024 + k0 + scol + 8];
    u16x8 b0 = *(const u16x8*)&Bw[(long)srow * 1024 + k0 + scol];
    u16x8 b1 = *(const u16x8*)&Bw[(long)srow * 1024 + k0 + scol + 8];
    __syncthreads();
    *(u16x8*)&Al[srow][scol]     = a0;
    *(u16x8*)&Al[srow][scol + 8] = a1;
    *(u16x8*)&Bl[srow][scol]     = b0;
    *(u16x8*)&Bl[srow][scol + 8] = b1;
    __syncthreads();
    bf16x8v af[4], bf[4];
#pragma unroll
    for (int i = 0; i < 4; ++i)
      af[i] = __builtin_bit_cast(bf16x8v, *(const u16x8*)&Al[wr * 64 + i * 16 + fr][ko * 8]);
#pragma unroll
    for (int jf = 0; jf < 4; ++jf)
      bf[jf] = __builtin_bit_cast(bf16x8v, *(const u16x8*)&Bl[wc * 64 + jf * 16 + fr][ko * 8]);
#pragma unroll
    for (int i = 0; i < 4; ++i)
#pragma unroll
      for (int jf = 0; jf < 4; ++jf)
        acc[i][jf] = __builtin_amdgcn_mfma_f32_16x16x32_bf16(af[i], bf[jf], acc[i][jf], 0, 0, 0);
  }
  int fq = lane >> 4;
#pragma unroll
  for (int i = 0; i < 4; ++i)
#pragma unroll
    for (int jf = 0; jf < 4; ++jf) {
      int col = wc * 64 + jf * 16 + fr;
      float bv = bias[col];
#pragma unroll
      for (int e = 0; e < 4; ++e) {
        int row = wr * 64 + i * 16 + fq * 4 + e;
        C[(long)row * 1024 + col] = acc[i][jf][e] + bv;
      }
    }
}

// ---------------------------------------------------------------------------
// Encoder v2: SELF-CONTAINED block per (dir, batch row). 256 blocks x 1024 thr.
// Thread c owns gate-col c, full K=256: w = 96 VGPR-pairs + 32 LDS-dwords.
// h lives in LDS (f16 pairs, double-buffered). Zero cross-block traffic.
__global__ __launch_bounds__(1024) void encoder_k(
    const u32* __restrict__ wf16t, const float* __restrict__ xp,
    float* h0b, float* h1b, float* cfb, float* cbb) {
  __shared__ u32 wl[16][1024][2];   // k-pairs 96..127 for each col: 128 KB
  __shared__ float red[1024];
  __shared__ u32 hl[2][128];        // h as f16 pairs, double-buffered
  int bid = blockIdx.x;
  int d = bid >> 7, row = bid & 127;
  int c = threadIdx.x;
  const u32* wsrc = wf16t + (long)d * (128 * 1024) + c;

  u32 w2[96];
#pragma unroll
  for (int kp = 0; kp < 96; ++kp) w2[kp] = wsrc[kp * 1024];
#pragma unroll
  for (int kq = 0; kq < 16; ++kq) {
    wl[kq][c][0] = wsrc[(96 + 2 * kq) * 1024];
    wl[kq][c][1] = wsrc[(97 + 2 * kq) * 1024];
  }
  if (c < 128) hl[0][c] = 0;
  float c_state = 0.f;
  const float* xpb = xp + ((long)d * 512 * 128 + row) * 1024 + c;
  float xpv = xpb[0];
  __syncthreads();

  for (int t = 0; t < 512; ++t) {
    int tn = (t + 1 < 512) ? (t + 1) : 511;
    float xnext = xpb[(long)tn * 131072];     // prefetch next step (HBM latency hide)
    int par = t & 1;
    const u32* hrow = &hl[par][0];
    float a0 = 0.f, a1 = 0.f, a2 = 0.f, a3 = 0.f;
#pragma unroll
    for (int kq = 0; kq < 24; ++kq) {         // VGPR weight part (broadcast h reads)
      u32 h0v = hrow[4 * kq + 0], h1v = hrow[4 * kq + 1];
      u32 h2v = hrow[4 * kq + 2], h3v = hrow[4 * kq + 3];
      a0 = dot2(h0v, w2[4 * kq + 0], a0);
      a1 = dot2(h1v, w2[4 * kq + 1], a1);
      a2 = dot2(h2v, w2[4 * kq + 2], a2);
      a3 = dot2(h3v, w2[4 * kq + 3], a3);
    }
#pragma unroll
    for (int kq = 0; kq < 16; ++kq) {         // LDS weight part
      u32 wp0 = wl[kq][c][0], wp1 = wl[kq][c][1];
      u32 hp0 = hrow[96 + 2 * kq], hp1 = hrow[97 + 2 * kq];
      a0 = dot2(hp0, wp0, a0);
      a1 = dot2(hp1, wp1, a1);
    }
    red[c] = a0 + a1 + a2 + a3 + xpv;
    xpv = xnext;
    __syncthreads();
    if (c < 256) {
      float gi = red[c], gf = red[256 + c], gg = red[512 + c], go = red[768 + c];
      float iv = 1.f / (1.f + expf(-gi));
      float fv = 1.f / (1.f + expf(-gf));
      float gt = tanhf(gg);
      float ov = 1.f / (1.f + expf(-go));
      c_state = fv * c_state + iv * gt;
      float hval = ov * tanhf(c_state);
      ((f16*)&hl[par ^ 1][0])[c] = (f16)hval;
      if (t == 511) {
        (d ? h1b : h0b)[32768 + row * 256 + c] = hval;  // parity-1 slot for decoder
        (d ? cbb : cfb)[row * 256 + c] = c_state;
      }
    }
    __syncthreads();
  }
}

// ---------------------------------------------------------------------------
// Decoder v2: 256 blocks = L(2) x bg(16) x jg(8), 512 thr. f16 dot2, weights
// resident in 64 VGPRs. Cross-block data via relaxed agent atomics (cache-
// bypassing); per-wave vmcnt drain + barrier before relaxed flag post.
__global__ __launch_bounds__(512) void decoder_k(
    const u32* __restrict__ dwf16, const float* __restrict__ dbias,
    float* h0b, float* h1b, float* inpb,
    const float* __restrict__ cfb, const float* __restrict__ cbb,
    float* hist, int* df) {
  int bid = blockIdx.x;
  int L = bid >> 7, bg = (bid >> 3) & 15, jg = bid & 7;
  int tid = threadIdx.x;
  int j = tid & 31, ks = tid >> 5;            // 16 k-slices of 32 (K=512)

  u32 w2[4][16];
  {
    const u32* p = dwf16 + (long)(L * 16 + ks) * 16384 + jg * 32 + j;
#pragma unroll
    for (int kp = 0; kp < 16; ++kp)
#pragma unroll
      for (int g = 0; g < 4; ++g)
        w2[g][kp] = p[(kp * 4 + g) * 256];
  }

  __shared__ u32 xl[8][256];                  // [inp|h] f16 pairs, 8 rows
  __shared__ float red[16][8][4][32];
  float c_state = 0.f;
  if (tid < 256)
    c_state = (L ? cbb : cfb)[(bg * 8 + (tid >> 5)) * 256 + jg * 32 + (tid & 31)];
  int srow = tid >> 6, sk8 = (tid & 63) * 8;

  for (int t = 0; t < 64; ++t) {
    if (tid < 16) {
      int p = tid & 7, which = tid >> 3;
      int need = (which == 0) ? ((L == 0) ? t : t + 1) : t;
      int* fp = &df[which * 128 + bg * 8 + p];
      while (__hip_atomic_load(fp, __ATOMIC_RELAXED, __HIP_MEMORY_SCOPE_AGENT) < need)
        __builtin_amdgcn_s_sleep(1);
      int vv = __hip_atomic_load(fp, __ATOMIC_ACQUIRE, __HIP_MEMORY_SCOPE_AGENT);
      asm volatile("" :: "v"(vv));
    }
    __syncthreads();
    {
      const float* xsrc  = (L == 0) ? inpb + (t & 1) * 32768 : h0b + (t & 1) * 32768;
      const float* hsrc2 = (L == 0) ? h0b + ((t + 1) & 1) * 32768 : h1b + ((t + 1) & 1) * 32768;
      const float* s = (sk8 < 256) ? &xsrc[(bg * 8 + srow) * 256 + sk8]
                                   : &hsrc2[(bg * 8 + srow) * 256 + sk8 - 256];
      u32 pk[4];
#pragma unroll
      for (int q = 0; q < 4; ++q) {
        float v0 = __hip_atomic_load(&s[2 * q],     __ATOMIC_RELAXED, __HIP_MEMORY_SCOPE_AGENT);
        float v1 = __hip_atomic_load(&s[2 * q + 1], __ATOMIC_RELAXED, __HIP_MEMORY_SCOPE_AGENT);
        pk[q] = packf16(v0, v1);
      }
      *(u32x4*)&xl[srow][(tid & 63) * 4] = (u32x4){pk[0], pk[1], pk[2], pk[3]};
    }
    __syncthreads();

    float acc[8][4] = {};
#pragma unroll
    for (int r = 0; r < 8; ++r) {
#pragma unroll
      for (int kc = 0; kc < 4; ++kc) {
        const u32* hq = &xl[r][ks * 16 + kc * 4];
        u32 q0 = hq[0], q1 = hq[1], q2 = hq[2], q3 = hq[3];
#pragma unroll
        for (int g = 0; g < 4; ++g) {
          acc[r][g] = dot2(q0, w2[g][kc * 4 + 0], acc[r][g]);
          acc[r][g] = dot2(q1, w2[g][kc * 4 + 1], acc[r][g]);
          acc[r][g] = dot2(q2, w2[g][kc * 4 + 2], acc[r][g]);
          acc[r][g] = dot2(q3, w2[g][kc * 4 + 3], acc[r][g]);
        }
      }
    }
#pragma unroll
    for (int r = 0; r < 8; ++r)
#pragma unroll
      for (int g = 0; g < 4; ++g)
        red[ks][r][g][j] = acc[r][g];
    __syncthreads();

    if (tid < 256) {
      int re = tid >> 5, je = tid & 31;
      float gv[4];
#pragma unroll
      for (int g = 0; g < 4; ++g) {
        float sum = dbias[L * 1024 + g * 256 + jg * 32 + je];
#pragma unroll
        for (int p = 0; p < 16; ++p) sum += red[p][re][g][je];
        gv[g] = sum;
      }
      float iv = 1.f / (1.f + expf(-gv[0]));
      float fv = 1.f / (1.f + expf(-gv[1]));
      float gt = tanhf(gv[2]);
      float ov = 1.f / (1.f + expf(-gv[3]));
      c_state = fv * c_state + iv * gt;
      float hval = ov * tanhf(c_state);
      int rowg = bg * 8 + re, colg = jg * 32 + je;
      if (L == 0) {
        __hip_atomic_store(&h0b[(t & 1) * 32768 + rowg * 256 + colg], hval,
                           __ATOMIC_RELAXED, __HIP_MEMORY_SCOPE_AGENT);
      } else {
        __hip_atomic_store(&h1b[(t & 1) * 32768 + rowg * 256 + colg], hval,
                           __ATOMIC_RELAXED, __HIP_MEMORY_SCOPE_AGENT);
        __hip_atomic_store(&inpb[((t + 1) & 1) * 32768 + rowg * 256 + colg], hval,
                           __ATOMIC_RELAXED, __HIP_MEMORY_SCOPE_AGENT);
        hist[((long)t * 128 + rowg) * 256 + colg] = hval;   // consumed after kernel end
      }
    }
    asm volatile("s_waitcnt vmcnt(0)" ::: "memory");  // per-wave: atomics complete at coherence point
    __syncthreads();
    if (tid == 0)
      __hip_atomic_store(&df[L * 128 + bg * 8 + jg], t + 1,
                         __ATOMIC_RELAXED, __HIP_MEMORY_SCOPE_AGENT);
  }
}

// ---------------------------------------------------------------------------
__global__ __launch_bounds__(256) void logits_k(
    const float* __restrict__ hist, const float* __restrict__ lw,
    const float* __restrict__ lb, float* __restrict__ out) {
  int widx = threadIdx.x >> 6, lane = threadIdx.x & 63;
  int row = blockIdx.x * 4 + widx;   // 0..8191 = t*128+b
  const float* h = hist + (long)row * 256;
  float4 hv = *(const float4*)&h[lane * 4];
  float s[3];
#pragma unroll
  for (int v = 0; v < 3; ++v) {
    float4 wv = *(const float4*)&lw[v * 256 + lane * 4];
    float p = hv.x * wv.x + hv.y * wv.y + hv.z * wv.z + hv.w * wv.w;
#pragma unroll
    for (int o = 32; o > 0; o >>= 1) p += __shfl_xor(p, o, 64);
    s[v] = p;
  }
  if (lane == 0) {
    out[row * 3 + 0] = s[0] + lb[0];
    out[row * 3 + 1] = s[1] + lb[1];
    out[row * 3 + 2] = s[2] + lb[2];
  }
}

// ---------------------------------------------------------------------------
extern "C" void kernel_launch(void* const* d_in, const int* in_sizes, int n_in,
                              void* d_out, int out_size, void* d_ws, size_t ws_size,
                              hipStream_t stream) {
  const float* x     = (const float*)d_in[0];
  const float* ewihf = (const float*)d_in[1];
  const float* ewhhf = (const float*)d_in[2];
  const float* ebihf = (const float*)d_in[3];
  const float* ebhhf = (const float*)d_in[4];
  const float* ewihb = (const float*)d_in[5];
  const float* ewhhb = (const float*)d_in[6];
  const float* ebihb = (const float*)d_in[7];
  const float* ebhhb = (const float*)d_in[8];
  const float* dwih0 = (const float*)d_in[9];
  const float* dwhh0 = (const float*)d_in[10];
  const float* dbih0 = (const float*)d_in[11];
  const float* dbhh0 = (const float*)d_in[12];
  const float* dwih1 = (const float*)d_in[13];
  const float* dwhh1 = (const float*)d_in[14];
  const float* dbih1 = (const float*)d_in[15];
  const float* dbhh1 = (const float*)d_in[16];
  const float* lw    = (const float*)d_in[17];
  const float* lb    = (const float*)d_in[18];
  float* out = (float*)d_out;
  (void)in_sizes; (void)n_in; (void)out_size; (void)ws_size;

  char* wsb = (char*)d_ws;
  size_t off = 0;
  auto take = [&](size_t bytes) -> char* {
    char* p = wsb + off;
    off = (off + bytes + 255) & ~(size_t)255;
    return p;
  };
  u16*   xbf   = (u16*)take(67108864ull * 2);    // x bf16
  u16*   wbf   = (u16*)take(2097152ull * 2);     // ew_ih f,b bf16
  float* xp    = (float*)take(134217728ull * 4); // Xproj [2][512][128][1024]
  u32*   wf16t = (u32*)take(262144ull * 4);      // enc W_hh f16 pairs [2][128][1024]
  u32*   dwf16 = (u32*)take(524288ull * 4);      // dec weights f16 pairs
  float* bias2 = (float*)take(2048 * 4);
  float* dbias = (float*)take(2048 * 4);
  float* h0b   = (float*)take(65536 * 4);        // [2 par][128][256]
  float* h1b   = (float*)take(65536 * 4);
  float* inpb  = (float*)take(65536 * 4);
  float* cfb   = (float*)take(32768 * 4);
  float* cbb   = (float*)take(32768 * 4);
  float* hist  = (float*)take(2097152 * 4);      // h1 history [64][128][256]
  int*   df    = (int*)take(256 * 4);

  init_k<<<256, 256, 0, stream>>>(inpb, df);
  convert_k<<<2048, 256, 0, stream>>>(x, ewihf, ewihb, ebihf, ebhhf, ebihb, ebhhb,
                                      dbih0, dbhh0, dbih1, dbhh1, xbf, wbf, bias2, dbias);
  convert_w_k<<<3072, 256, 0, stream>>>(ewhhf, ewhhb, dwih0, dwhh0, dwih1, dwhh1,
                                        wf16t, dwf16);
  xproj_gemm<<<8192, 256, 0, stream>>>(xbf, wbf, bias2, xp);
  encoder_k<<<256, 1024, 0, stream>>>(wf16t, xp, h0b, h1b, cfb, cbb);
  decoder_k<<<256, 512, 0, stream>>>(dwf16, dbias, h0b, h1b, inpb, cfb, cbb, hist, df);
  logits_k<<<2048, 256, 0, stream>>>(hist, lw, lb, out);
}

// Round 4
// 2967.046 us; speedup vs baseline: 4.8808x; 4.8808x over previous
//
#include <hip/hip_runtime.h>
#include <hip/hip_bf16.h>
#include <math.h>

// ---------------------------------------------------------------------------
// Bi-LSTM encoder (final states only) -> 2-layer AR decoder (64 steps) -> vocab-3.
//   init_k       : zero decoder input buffer / sync flags (every call)
//   convert_k    : x, ew_ih_{f,b} -> f16; bias sums
//   convert_we_k : enc W_hh -> MFMA B-fragments (f16)
//   convert_wd_k : dec [W_ih|W_hh] -> packed f16 pairs (R2-proven layout)
//   xproj_gemm   : f16 MFMA GEMM -> Xproj[dir][t][b][1024] fp32 (+bias), dir1 reversed
//   encoder_k    : 256 blocks (d x bg x cg), MFMA recurrence, weights = 32 VGPR frags,
//                  h all-gather among 16 sibling blocks via relaxed agent atomics
//   decoder_k    : persistent (L,bg,jg) blocks, f16 dot2, relaxed-atomic flag sync
//   logits_k     : h1 history @ lw^T + lb
// ---------------------------------------------------------------------------

typedef unsigned short u16;
typedef unsigned int u32;
typedef unsigned long long u64;
typedef _Float16 f16;
typedef f16 f16x8 __attribute__((ext_vector_type(8)));
typedef f16 f16x2 __attribute__((ext_vector_type(2)));
typedef u16 u16x8 __attribute__((ext_vector_type(8)));
typedef u32 u32x4 __attribute__((ext_vector_type(4)));
typedef float f32x4 __attribute__((ext_vector_type(4)));

__device__ __forceinline__ u16 f2h(float f) {
  return __builtin_bit_cast(unsigned short, (f16)f);
}
__device__ __forceinline__ u32 packf16(float a, float b) {
  return (u32)f2h(a) | ((u32)f2h(b) << 16);
}
__device__ __forceinline__ float dot2(u32 h, u32 w, float c) {
  return __builtin_amdgcn_fdot2(__builtin_bit_cast(f16x2, h),
                                __builtin_bit_cast(f16x2, w), c, false);
}

// ---------------------------------------------------------------------------
__global__ __launch_bounds__(256) void init_k(float* inpb, int* ef, int* df) {
  int gid = blockIdx.x * 256 + threadIdx.x;   // grid 256*256 = 65536
  inpb[gid] = 0.f;
  if (gid < 256) { ef[gid] = 0; df[gid] = 0; }
}

// ---------------------------------------------------------------------------
__global__ __launch_bounds__(256) void convert_k(
    const float* __restrict__ x,
    const float* __restrict__ wfm, const float* __restrict__ wbm,
    const float* __restrict__ bif, const float* __restrict__ bhf,
    const float* __restrict__ bib, const float* __restrict__ bhb,
    const float* __restrict__ dbi0, const float* __restrict__ dbh0,
    const float* __restrict__ dbi1, const float* __restrict__ dbh1,
    u16* __restrict__ xh, u16* __restrict__ wh,
    float* __restrict__ bias2, float* __restrict__ dbias) {
  const long NX = 67108864L, NW = 1048576L;
  long gid = (long)blockIdx.x * 256 + threadIdx.x;
  if (gid < 1024) {
    bias2[gid]        = bif[gid] + bhf[gid];
    bias2[1024 + gid] = bib[gid] + bhb[gid];
    dbias[gid]        = dbi0[gid] + dbh0[gid];
    dbias[1024 + gid] = dbi1[gid] + dbh1[gid];
  }
  long total4 = (NX + 2 * NW) >> 2;
  long stride = (long)gridDim.x * 256;
  for (long q = gid; q < total4; q += stride) {
    long i = q << 2;
    const float* src; u16* dst; long o;
    if (i < NX)            { src = x;   dst = xh;      o = i; }
    else if (i < NX + NW)  { src = wfm; dst = wh;      o = i - NX; }
    else                   { src = wbm; dst = wh + NW; o = i - NX - NW; }
    float4 v = *(const float4*)&src[o];
    dst[o + 0] = f2h(v.x); dst[o + 1] = f2h(v.y);
    dst[o + 2] = f2h(v.z); dst[o + 3] = f2h(v.w);
  }
}

// ---------------------------------------------------------------------------
// enc W_hh -> MFMA B-fragments: wencf[d][cg][g][ks][lane][j] =
//   W_hh_d[g*256+cg*16+(lane&15)][ks*32+(lane>>4)*8+j]   (f16)
__global__ __launch_bounds__(256) void convert_we_k(
    const float* __restrict__ whf, const float* __restrict__ whb,
    u16* __restrict__ wencf) {
  int o = blockIdx.x * 256 + threadIdx.x;     // grid 2048*256 = 524288
  int j = o & 7, lane = (o >> 3) & 63, ks = (o >> 9) & 7;
  int g = (o >> 12) & 3, cg = (o >> 14) & 15, d = o >> 18;
  const float* w = d ? whb : whf;
  int row = g * 256 + cg * 16 + (lane & 15);
  int k = ks * 32 + (lane >> 4) * 8 + j;
  wencf[o] = f2h(w[row * 256 + k]);
}

// ---------------------------------------------------------------------------
// dec [W_ih|W_hh] -> packed f16 pairs: dwf16[L(2)][ks(16)][kp(16)][g(4)][c(256)]
// strides 262144 / 16384 / 1024 / 256 / 1  (R2-proven; matches decoder_k reads)
__global__ __launch_bounds__(256) void convert_wd_k(
    const float* __restrict__ wi0, const float* __restrict__ wh0,
    const float* __restrict__ wi1, const float* __restrict__ wh1,
    u32* __restrict__ dwf16) {
  int i = blockIdx.x * 256 + threadIdx.x;     // grid 2048*256 = 524288
  int L = i >> 18, ks = (i >> 14) & 15, kp = (i >> 10) & 15;
  int g = (i >> 8) & 3, c = i & 255;
  int grow = g * 256 + c;
  int kk = (ks * 16 + kp) * 2;
  const float* wi = L ? wi1 : wi0;
  const float* wh = L ? wh1 : wh0;
  const float* s = (kk < 256) ? &wi[grow * 256 + kk] : &wh[grow * 256 + kk - 256];
  dwf16[i] = packf16(s[0], s[1]);
}

// ---------------------------------------------------------------------------
// Xproj GEMM (f16): C = X @ W^T + bias, 128x128 tiles, mfma_f32_16x16x32_f16.
__global__ __launch_bounds__(256) void xproj_gemm(
    const u16* __restrict__ xh, const u16* __restrict__ wh,
    const float* __restrict__ bias2, float* __restrict__ xp) {
  __shared__ u16 Al[128][40];
  __shared__ u16 Bl[128][40];
  int bid = blockIdx.x;
  int dir = bid >> 12, rem = bid & 4095, tb = rem >> 3, nb = rem & 7;
  int tsrc = dir ? (511 - tb) : tb;
  const u16* A  = xh + (long)tsrc * (128 * 1024);
  const u16* Bw = wh + (long)dir * (1024 * 1024) + (long)nb * (128 * 1024);
  float* C = xp + ((long)(dir * 512 + tb) * 128) * 1024 + nb * 128;
  const float* bias = bias2 + dir * 1024 + nb * 128;

  int tid = threadIdx.x, lane = tid & 63, wid = tid >> 6;
  int wr = wid >> 1, wc = wid & 1;
  int srow = tid >> 1, scol = (tid & 1) * 16;
  int fr = lane & 15, ko = lane >> 4;

  f32x4 acc[4][4] = {};
  for (int k0 = 0; k0 < 1024; k0 += 32) {
    u16x8 a0 = *(const u16x8*)&A[(long)srow * 1024 + k0 + scol];
    u16x8 a1 = *(const u16x8*)&A[(long)srow * 1024 + k0 + scol + 8];
    u16x8 b0 = *(const u16x8*)&Bw[(long)srow * 1024 + k0 + scol];
    u16x8 b1 = *(const u16x8*)&Bw[(long)srow * 1024 + k0 + scol + 8];
    __syncthreads();
    *(u16x8*)&Al[srow][scol]     = a0;
    *(u16x8*)&Al[srow][scol + 8] = a1;
    *(u16x8*)&Bl[srow][scol]     = b0;
    *(u16x8*)&Bl[srow][scol + 8] = b1;
    __syncthreads();
    f16x8 af[4], bf[4];
#pragma unroll
    for (int i = 0; i < 4; ++i)
      af[i] = __builtin_bit_cast(f16x8, *(const u16x8*)&Al[wr * 64 + i * 16 + fr][ko * 8]);
#pragma unroll
    for (int jf = 0; jf < 4; ++jf)
      bf[jf] = __builtin_bit_cast(f16x8, *(const u16x8*)&Bl[wc * 64 + jf * 16 + fr][ko * 8]);
#pragma unroll
    for (int i = 0; i < 4; ++i)
#pragma unroll
      for (int jf = 0; jf < 4; ++jf)
        acc[i][jf] = __builtin_amdgcn_mfma_f32_16x16x32_f16(af[i], bf[jf], acc[i][jf], 0, 0, 0);
  }
  int fq = lane >> 4;
#pragma unroll
  for (int i = 0; i < 4; ++i)
#pragma unroll
    for (int jf = 0; jf < 4; ++jf) {
      int col = wc * 64 + jf * 16 + fr;
      float bv = bias[col];
#pragma unroll
      for (int e = 0; e < 4; ++e) {
        int row = wr * 64 + i * 16 + fq * 4 + e;
        C[(long)row * 1024 + col] = acc[i][jf][e] + bv;
      }
    }
}

// ---------------------------------------------------------------------------
// Encoder v3: 256 blocks = d(2) x bg(8; 16 rows) x cg(16; 16 hcols), 256 thr.
// Wave g holds W_hh B-frags (8 x f16x8 = 32 VGPR). Per step: 8 MFMA 16x16x32_f16.
// h_t in LDS (f16, XOR-swizzled). All-gather among 16 sibling blocks via
// relaxed agent atomics; flag posted after per-wave vmcnt(0) drain + barrier.
__global__ __launch_bounds__(256, 1) void encoder_k(
    const u16* __restrict__ wencf, const float* __restrict__ xp,
    u32* hglob, int* ef,
    float* h0b, float* h1b, float* cfb, float* cbb) {
  int b = blockIdx.x;
  int g16 = ((b >> 7) << 3) | (b & 7);        // group (d,bg): 16 cg siblings share blockIdx%8
  int cg = (b >> 3) & 15;
  int d = g16 >> 3, bg = g16 & 7;
  int tid = threadIdx.x, lane = tid & 63, wid = tid >> 6;   // wid = gate g
  int r_t = tid >> 4, cc = tid & 15;          // epilogue cell (batch row, hcol)

  __shared__ __align__(16) char hlds[2][8192];   // h [16 r][256 k f16], XOR-swizzled
  __shared__ float red[4 * 16 * 20];             // [g][n-col][20 pad] -> D[m][n]

  f16x8 bfrag[8];                                // 32 VGPRs, statically indexed
  {
    const u16* wp = wencf + ((long)(d * 16 + cg) * 4 + wid) * 4096 + lane * 8;
#pragma unroll
    for (int ks = 0; ks < 8; ++ks)
      bfrag[ks] = __builtin_bit_cast(f16x8, *(const u16x8*)&wp[ks * 512]);
  }
#pragma unroll
  for (int q = 0; q < 4; ++q)
    *(u64*)(hlds[0] + tid * 8 + q * 2048) = 0ull;   // h_0 = 0

  float c_state = 0.f;
  long xpbase = ((long)(d * 512) * 128 + bg * 16 + r_t) * 1024 + cg * 16 + cc;
  float xpv[4], xnext[4];
#pragma unroll
  for (int g = 0; g < 4; ++g) xpv[g] = xp[xpbase + g * 256];
  u64* hgu64 = (u64*)hglob;
  __syncthreads();

  for (int t = 0; t < 512; ++t) {
    int par = t & 1;
    f32x4 acc = {};
    if (t != 0) {
      const char* hp = hlds[par];
      int abase = (lane & 15) * 512 + (lane >> 4) * 16;
      int axor = (lane & 7) << 4;
#pragma unroll
      for (int ks = 0; ks < 8; ++ks) {
        f16x8 af = *(const f16x8*)(hp + ((abase + ks * 64) ^ axor));
        acc = __builtin_amdgcn_mfma_f32_16x16x32_f16(af, bfrag[ks], acc, 0, 0, 0);
      }
    }
    *(f32x4*)&red[(wid * 16 + (lane & 15)) * 20 + (lane >> 4) * 4] = acc;
    __syncthreads();

    float gv[4];
#pragma unroll
    for (int g = 0; g < 4; ++g) gv[g] = red[(g * 16 + cc) * 20 + r_t] + xpv[g];
    float iv = 1.f / (1.f + expf(-gv[0]));
    float fv = 1.f / (1.f + expf(-gv[1]));
    float gt = tanhf(gv[2]);
    float ov = 1.f / (1.f + expf(-gv[3]));
    c_state = fv * c_state + iv * gt;
    float hval = ov * tanhf(c_state);

    if (t < 511) {
      u16 hb = f2h(hval);
      int ph = __shfl_xor((int)hb, 1);
      if ((cc & 1) == 0) {
        u32 pk = (u32)hb | (((u32)ph & 0xffffu) << 16);
        __hip_atomic_store(&hglob[g16 * 4096 + (par ^ 1) * 2048 + r_t * 128 + cg * 8 + (cc >> 1)],
                           pk, __ATOMIC_RELAXED, __HIP_MEMORY_SCOPE_AGENT);
      }
      asm volatile("s_waitcnt vmcnt(0)" ::: "memory");
      __syncthreads();
      if (tid == 0)
        __hip_atomic_store(&ef[g16 * 16 + cg], t + 1,
                           __ATOMIC_RELAXED, __HIP_MEMORY_SCOPE_AGENT);
      long xb2 = xpbase + (long)(t + 1) * 131072;   // prefetch during sibling wait
#pragma unroll
      for (int g = 0; g < 4; ++g) xnext[g] = xp[xb2 + g * 256];
      if (tid < 16) {
        int* fp = &ef[g16 * 16 + tid];
        while (__hip_atomic_load(fp, __ATOMIC_RELAXED, __HIP_MEMORY_SCOPE_AGENT) < t + 1)
          __builtin_amdgcn_s_sleep(1);
      }
      __syncthreads();
      {
        char* hpn = hlds[par ^ 1];
        int r2 = tid >> 4, jj = tid & 15;
        long gbase = (long)g16 * 2048 + (par ^ 1) * 1024 + r2 * 64 + jj * 4;
        int lbase = r2 * 512 + jj * 32;
        int lxor = (r2 & 7) << 4;
#pragma unroll
        for (int q = 0; q < 4; ++q) {
          u64 v = __hip_atomic_load(&hgu64[gbase + q], __ATOMIC_RELAXED, __HIP_MEMORY_SCOPE_AGENT);
          *(u64*)(hpn + ((lbase + q * 8) ^ lxor)) = v;
        }
      }
      __syncthreads();
#pragma unroll
      for (int g = 0; g < 4; ++g) xpv[g] = xnext[g];
    } else {
      int rowg = bg * 16 + r_t, colg = cg * 16 + cc;
      (d ? h1b : h0b)[32768 + rowg * 256 + colg] = hval;
      (d ? cbb : cfb)[rowg * 256 + colg] = c_state;
    }
  }
}

// ---------------------------------------------------------------------------
// Decoder (R2, proven): 256 blocks = L(2) x bg(16) x jg(8), 512 thr.
__global__ __launch_bounds__(512) void decoder_k(
    const u32* __restrict__ dwf16, const float* __restrict__ dbias,
    float* h0b, float* h1b, float* inpb,
    const float* __restrict__ cfb, const float* __restrict__ cbb,
    float* hist, int* df) {
  int bid = blockIdx.x;
  int L = bid >> 7, bg = (bid >> 3) & 15, jg = bid & 7;
  int tid = threadIdx.x;
  int j = tid & 31, ks = tid >> 5;

  u32 w2[4][16];
  {
    const u32* p = dwf16 + (long)(L * 16 + ks) * 16384 + jg * 32 + j;
#pragma unroll
    for (int kp = 0; kp < 16; ++kp)
#pragma unroll
      for (int g = 0; g < 4; ++g)
        w2[g][kp] = p[(kp * 4 + g) * 256];
  }

  __shared__ u32 xl[8][256];
  __shared__ float red[16][8][4][32];
  float c_state = 0.f;
  if (tid < 256)
    c_state = (L ? cbb : cfb)[(bg * 8 + (tid >> 5)) * 256 + jg * 32 + (tid & 31)];
  int srow = tid >> 6, sk8 = (tid & 63) * 8;

  for (int t = 0; t < 64; ++t) {
    if (tid < 16) {
      int p = tid & 7, which = tid >> 3;
      int need = (which == 0) ? ((L == 0) ? t : t + 1) : t;
      int* fp = &df[which * 128 + bg * 8 + p];
      while (__hip_atomic_load(fp, __ATOMIC_RELAXED, __HIP_MEMORY_SCOPE_AGENT) < need)
        __builtin_amdgcn_s_sleep(1);
    }
    __syncthreads();
    {
      const float* xsrc  = (L == 0) ? inpb + (t & 1) * 32768 : h0b + (t & 1) * 32768;
      const float* hsrc2 = (L == 0) ? h0b + ((t + 1) & 1) * 32768 : h1b + ((t + 1) & 1) * 32768;
      const float* s = (sk8 < 256) ? &xsrc[(bg * 8 + srow) * 256 + sk8]
                                   : &hsrc2[(bg * 8 + srow) * 256 + sk8 - 256];
      u32 pk[4];
#pragma unroll
      for (int q = 0; q < 4; ++q) {
        float v0 = __hip_atomic_load(&s[2 * q],     __ATOMIC_RELAXED, __HIP_MEMORY_SCOPE_AGENT);
        float v1 = __hip_atomic_load(&s[2 * q + 1], __ATOMIC_RELAXED, __HIP_MEMORY_SCOPE_AGENT);
        pk[q] = packf16(v0, v1);
      }
      *(u32x4*)&xl[srow][(tid & 63) * 4] = (u32x4){pk[0], pk[1], pk[2], pk[3]};
    }
    __syncthreads();

    float acc[8][4] = {};
#pragma unroll
    for (int r = 0; r < 8; ++r) {
#pragma unroll
      for (int kc = 0; kc < 4; ++kc) {
        const u32* hq = &xl[r][ks * 16 + kc * 4];
        u32 q0 = hq[0], q1 = hq[1], q2 = hq[2], q3 = hq[3];
#pragma unroll
        for (int g = 0; g < 4; ++g) {
          acc[r][g] = dot2(q0, w2[g][kc * 4 + 0], acc[r][g]);
          acc[r][g] = dot2(q1, w2[g][kc * 4 + 1], acc[r][g]);
          acc[r][g] = dot2(q2, w2[g][kc * 4 + 2], acc[r][g]);
          acc[r][g] = dot2(q3, w2[g][kc * 4 + 3], acc[r][g]);
        }
      }
    }
#pragma unroll
    for (int r = 0; r < 8; ++r)
#pragma unroll
      for (int g = 0; g < 4; ++g)
        red[ks][r][g][j] = acc[r][g];
    __syncthreads();

    if (tid < 256) {
      int re = tid >> 5, je = tid & 31;
      float gv[4];
#pragma unroll
      for (int g = 0; g < 4; ++g) {
        float sum = dbias[L * 1024 + g * 256 + jg * 32 + je];
#pragma unroll
        for (int p = 0; p < 16; ++p) sum += red[p][re][g][je];
        gv[g] = sum;
      }
      float iv = 1.f / (1.f + expf(-gv[0]));
      float fv = 1.f / (1.f + expf(-gv[1]));
      float gt = tanhf(gv[2]);
      float ov = 1.f / (1.f + expf(-gv[3]));
      c_state = fv * c_state + iv * gt;
      float hval = ov * tanhf(c_state);
      int rowg = bg * 8 + re, colg = jg * 32 + je;
      if (L == 0) {
        __hip_atomic_store(&h0b[(t & 1) * 32768 + rowg * 256 + colg], hval,
                           __ATOMIC_RELAXED, __HIP_MEMORY_SCOPE_AGENT);
      } else {
        __hip_atomic_store(&h1b[(t & 1) * 32768 + rowg * 256 + colg], hval,
                           __ATOMIC_RELAXED, __HIP_MEMORY_SCOPE_AGENT);
        __hip_atomic_store(&inpb[((t + 1) & 1) * 32768 + rowg * 256 + colg], hval,
                           __ATOMIC_RELAXED, __HIP_MEMORY_SCOPE_AGENT);
        hist[((long)t * 128 + rowg) * 256 + colg] = hval;
      }
    }
    asm volatile("s_waitcnt vmcnt(0)" ::: "memory");
    __syncthreads();
    if (tid == 0)
      __hip_atomic_store(&df[L * 128 + bg * 8 + jg], t + 1,
                         __ATOMIC_RELAXED, __HIP_MEMORY_SCOPE_AGENT);
  }
}

// ---------------------------------------------------------------------------
__global__ __launch_bounds__(256) void logits_k(
    const float* __restrict__ hist, const float* __restrict__ lw,
    const float* __restrict__ lb, float* __restrict__ out) {
  int widx = threadIdx.x >> 6, lane = threadIdx.x & 63;
  int row = blockIdx.x * 4 + widx;
  const float* h = hist + (long)row * 256;
  float4 hv = *(const float4*)&h[lane * 4];
  float s[3];
#pragma unroll
  for (int v = 0; v < 3; ++v) {
    float4 wv = *(const float4*)&lw[v * 256 + lane * 4];
    float p = hv.x * wv.x + hv.y * wv.y + hv.z * wv.z + hv.w * wv.w;
#pragma unroll
    for (int o = 32; o > 0; o >>= 1) p += __shfl_xor(p, o, 64);
    s[v] = p;
  }
  if (lane == 0) {
    out[row * 3 + 0] = s[0] + lb[0];
    out[row * 3 + 1] = s[1] + lb[1];
    out[row * 3 + 2] = s[2] + lb[2];
  }
}

// ---------------------------------------------------------------------------
extern "C" void kernel_launch(void* const* d_in, const int* in_sizes, int n_in,
                              void* d_out, int out_size, void* d_ws, size_t ws_size,
                              hipStream_t stream) {
  const float* x     = (const float*)d_in[0];
  const float* ewihf = (const float*)d_in[1];
  const float* ewhhf = (const float*)d_in[2];
  const float* ebihf = (const float*)d_in[3];
  const float* ebhhf = (const float*)d_in[4];
  const float* ewihb = (const float*)d_in[5];
  const float* ewhhb = (const float*)d_in[6];
  const float* ebihb = (const float*)d_in[7];
  const float* ebhhb = (const float*)d_in[8];
  const float* dwih0 = (const float*)d_in[9];
  const float* dwhh0 = (const float*)d_in[10];
  const float* dbih0 = (const float*)d_in[11];
  const float* dbhh0 = (const float*)d_in[12];
  const float* dwih1 = (const float*)d_in[13];
  const float* dwhh1 = (const float*)d_in[14];
  const float* dbih1 = (const float*)d_in[15];
  const float* dbhh1 = (const float*)d_in[16];
  const float* lw    = (const float*)d_in[17];
  const float* lb    = (const float*)d_in[18];
  float* out = (float*)d_out;
  (void)in_sizes; (void)n_in; (void)out_size; (void)ws_size;

  char* wsb = (char*)d_ws;
  size_t off = 0;
  auto take = [&](size_t bytes) -> char* {
    char* p = wsb + off;
    off = (off + bytes + 255) & ~(size_t)255;
    return p;
  };
  u16*   xh    = (u16*)take(67108864ull * 2);    // x f16
  u16*   whx   = (u16*)take(2097152ull * 2);     // ew_ih f,b f16
  float* xp    = (float*)take(134217728ull * 4); // Xproj [2][512][128][1024] fp32
  u16*   wencf = (u16*)take(524288ull * 2);      // enc W_hh MFMA frags
  u32*   dwf16 = (u32*)take(524288ull * 4);      // dec weights f16 pairs [2][16][16][4][256]
  float* bias2 = (float*)take(2048 * 4);
  float* dbias = (float*)take(2048 * 4);
  u32*   hglob = (u32*)take(65536ull * 4);       // enc h exchange [16g][2 par][16r][128]
  float* h0b   = (float*)take(65536 * 4);
  float* h1b   = (float*)take(65536 * 4);
  float* inpb  = (float*)take(65536 * 4);
  float* cfb   = (float*)take(32768 * 4);
  float* cbb   = (float*)take(32768 * 4);
  float* hist  = (float*)take(2097152 * 4);
  int*   ef    = (int*)take(256 * 4);
  int*   df    = (int*)take(256 * 4);

  init_k<<<256, 256, 0, stream>>>(inpb, ef, df);
  convert_k<<<2048, 256, 0, stream>>>(x, ewihf, ewihb, ebihf, ebhhf, ebihb, ebhhb,
                                      dbih0, dbhh0, dbih1, dbhh1, xh, whx, bias2, dbias);
  convert_we_k<<<2048, 256, 0, stream>>>(ewhhf, ewhhb, wencf);
  convert_wd_k<<<2048, 256, 0, stream>>>(dwih0, dwhh0, dwih1, dwhh1, dwf16);
  xproj_gemm<<<8192, 256, 0, stream>>>(xh, whx, bias2, xp);
  encoder_k<<<256, 256, 0, stream>>>(wencf, xp, hglob, ef, h0b, h1b, cfb, cbb);
  decoder_k<<<256, 512, 0, stream>>>(dwf16, dbias, h0b, h1b, inpb, cfb, cbb, hist, df);
  logits_k<<<2048, 256, 0, stream>>>(hist, lw, lb, out);
}

// Round 6
// 2781.582 us; speedup vs baseline: 5.2063x; 1.0667x over previous
//
#include <hip/hip_runtime.h>
#include <hip/hip_bf16.h>
#include <math.h>

// ---------------------------------------------------------------------------
// Bi-LSTM encoder (final states only) -> 2-layer AR decoder (64 steps) -> vocab-3.
//   init_k       : zero decoder input buf / flags; sentinel the encoder h-ring
//   convert_k    : x, ew_ih_{f,b} -> f16; bias sums
//   convert_we_k : enc W_hh -> MFMA B-fragments (f16)
//   convert_wd_k : dec [W_ih|W_hh] -> packed f16 pairs
//   xproj_gemm   : f16 MFMA GEMM -> Xproj[dir][t][b][1024] fp32 (+bias), dir1 reversed
//   encoder_k    : v5 — sentinel-poll exchange over a DEPTH-4 ring (re-arm 2 slots
//                  ahead; vmcnt(0) release chain makes stale-read impossible),
//                  MFMA recurrence, W_hh frags resident in 32 VGPRs
//   decoder_k    : persistent (L,bg,jg) blocks, f16 dot2, relaxed-atomic flag sync
//   logits_k     : h1 history @ lw^T + lb
// ---------------------------------------------------------------------------

typedef unsigned short u16;
typedef unsigned int u32;
typedef unsigned long long u64;
typedef _Float16 f16;
typedef f16 f16x8 __attribute__((ext_vector_type(8)));
typedef f16 f16x2 __attribute__((ext_vector_type(2)));
typedef u16 u16x8 __attribute__((ext_vector_type(8)));
typedef u32 u32x4 __attribute__((ext_vector_type(4)));
typedef float f32x4 __attribute__((ext_vector_type(4)));

__device__ __forceinline__ u16 f2h(float f) {
  return __builtin_bit_cast(unsigned short, (f16)f);
}
__device__ __forceinline__ u32 packf16(float a, float b) {
  return (u32)f2h(a) | ((u32)f2h(b) << 16);
}
__device__ __forceinline__ float dot2(u32 h, u32 w, float c) {
  return __builtin_amdgcn_fdot2(__builtin_bit_cast(f16x2, h),
                                __builtin_bit_cast(f16x2, w), c, false);
}
__device__ __forceinline__ u64 ald64(const u64* p) {
  return __hip_atomic_load(p, __ATOMIC_RELAXED, __HIP_MEMORY_SCOPE_AGENT);
}
__device__ __forceinline__ void ast64(u64* p, u64 v) {
  __hip_atomic_store(p, v, __ATOMIC_RELAXED, __HIP_MEMORY_SCOPE_AGENT);
}

#define SENT 0xFFFFFFFFFFFFFFFFull   // f16 NaN pair: unreachable for h in (-1,1)

// ---------------------------------------------------------------------------
__global__ __launch_bounds__(256) void init_k(float* inpb, u32* hglob, int* df) {
  int gid = blockIdx.x * 256 + threadIdx.x;   // grid 512*256 = 131072
  hglob[gid] = 0xFFFFFFFFu;                   // sentinel all 4 ring slots
  if (gid < 65536) inpb[gid] = 0.f;
  if (gid < 256) df[gid] = 0;
}

// ---------------------------------------------------------------------------
__global__ __launch_bounds__(256) void convert_k(
    const float* __restrict__ x,
    const float* __restrict__ wfm, const float* __restrict__ wbm,
    const float* __restrict__ bif, const float* __restrict__ bhf,
    const float* __restrict__ bib, const float* __restrict__ bhb,
    const float* __restrict__ dbi0, const float* __restrict__ dbh0,
    const float* __restrict__ dbi1, const float* __restrict__ dbh1,
    u16* __restrict__ xh, u16* __restrict__ wh,
    float* __restrict__ bias2, float* __restrict__ dbias) {
  const long NX = 67108864L, NW = 1048576L;
  long gid = (long)blockIdx.x * 256 + threadIdx.x;
  if (gid < 1024) {
    bias2[gid]        = bif[gid] + bhf[gid];
    bias2[1024 + gid] = bib[gid] + bhb[gid];
    dbias[gid]        = dbi0[gid] + dbh0[gid];
    dbias[1024 + gid] = dbi1[gid] + dbh1[gid];
  }
  long total4 = (NX + 2 * NW) >> 2;
  long stride = (long)gridDim.x * 256;
  for (long q = gid; q < total4; q += stride) {
    long i = q << 2;
    const float* src; u16* dst; long o;
    if (i < NX)            { src = x;   dst = xh;      o = i; }
    else if (i < NX + NW)  { src = wfm; dst = wh;      o = i - NX; }
    else                   { src = wbm; dst = wh + NW; o = i - NX - NW; }
    float4 v = *(const float4*)&src[o];
    dst[o + 0] = f2h(v.x); dst[o + 1] = f2h(v.y);
    dst[o + 2] = f2h(v.z); dst[o + 3] = f2h(v.w);
  }
}

// ---------------------------------------------------------------------------
// enc W_hh -> MFMA B-fragments: wencf[d][cg][g][ks][lane][j] =
//   W_hh_d[g*256+cg*16+(lane&15)][ks*32+(lane>>4)*8+j]   (f16)
__global__ __launch_bounds__(256) void convert_we_k(
    const float* __restrict__ whf, const float* __restrict__ whb,
    u16* __restrict__ wencf) {
  int o = blockIdx.x * 256 + threadIdx.x;     // grid 2048*256 = 524288
  int j = o & 7, lane = (o >> 3) & 63, ks = (o >> 9) & 7;
  int g = (o >> 12) & 3, cg = (o >> 14) & 15, d = o >> 18;
  const float* w = d ? whb : whf;
  int row = g * 256 + cg * 16 + (lane & 15);
  int k = ks * 32 + (lane >> 4) * 8 + j;
  wencf[o] = f2h(w[row * 256 + k]);
}

// ---------------------------------------------------------------------------
// dec [W_ih|W_hh] -> packed f16 pairs: dwf16[L(2)][ks(16)][kp(16)][g(4)][c(256)]
__global__ __launch_bounds__(256) void convert_wd_k(
    const float* __restrict__ wi0, const float* __restrict__ wh0,
    const float* __restrict__ wi1, const float* __restrict__ wh1,
    u32* __restrict__ dwf16) {
  int i = blockIdx.x * 256 + threadIdx.x;     // grid 2048*256 = 524288
  int L = i >> 18, ks = (i >> 14) & 15, kp = (i >> 10) & 15;
  int g = (i >> 8) & 3, c = i & 255;
  int grow = g * 256 + c;
  int kk = (ks * 16 + kp) * 2;
  const float* wi = L ? wi1 : wi0;
  const float* wh = L ? wh1 : wh0;
  const float* s = (kk < 256) ? &wi[grow * 256 + kk] : &wh[grow * 256 + kk - 256];
  dwf16[i] = packf16(s[0], s[1]);
}

// ---------------------------------------------------------------------------
// Xproj GEMM (f16): C = X @ W^T + bias, 128x128 tiles, mfma_f32_16x16x32_f16.
__global__ __launch_bounds__(256) void xproj_gemm(
    const u16* __restrict__ xh, const u16* __restrict__ wh,
    const float* __restrict__ bias2, float* __restrict__ xp) {
  __shared__ u16 Al[128][40];
  __shared__ u16 Bl[128][40];
  int bid = blockIdx.x;
  int dir = bid >> 12, rem = bid & 4095, tb = rem >> 3, nb = rem & 7;
  int tsrc = dir ? (511 - tb) : tb;
  const u16* A  = xh + (long)tsrc * (128 * 1024);
  const u16* Bw = wh + (long)dir * (1024 * 1024) + (long)nb * (128 * 1024);
  float* C = xp + ((long)(dir * 512 + tb) * 128) * 1024 + nb * 128;
  const float* bias = bias2 + dir * 1024 + nb * 128;

  int tid = threadIdx.x, lane = tid & 63, wid = tid >> 6;
  int wr = wid >> 1, wc = wid & 1;
  int srow = tid >> 1, scol = (tid & 1) * 16;
  int fr = lane & 15, ko = lane >> 4;

  f32x4 acc[4][4] = {};
  for (int k0 = 0; k0 < 1024; k0 += 32) {
    u16x8 a0 = *(const u16x8*)&A[(long)srow * 1024 + k0 + scol];
    u16x8 a1 = *(const u16x8*)&A[(long)srow * 1024 + k0 + scol + 8];
    u16x8 b0 = *(const u16x8*)&Bw[(long)srow * 1024 + k0 + scol];
    u16x8 b1 = *(const u16x8*)&Bw[(long)srow * 1024 + k0 + scol + 8];
    __syncthreads();
    *(u16x8*)&Al[srow][scol]     = a0;
    *(u16x8*)&Al[srow][scol + 8] = a1;
    *(u16x8*)&Bl[srow][scol]     = b0;
    *(u16x8*)&Bl[srow][scol + 8] = b1;
    __syncthreads();
    f16x8 af[4], bf[4];
#pragma unroll
    for (int i = 0; i < 4; ++i)
      af[i] = __builtin_bit_cast(f16x8, *(const u16x8*)&Al[wr * 64 + i * 16 + fr][ko * 8]);
#pragma unroll
    for (int jf = 0; jf < 4; ++jf)
      bf[jf] = __builtin_bit_cast(f16x8, *(const u16x8*)&Bl[wc * 64 + jf * 16 + fr][ko * 8]);
#pragma unroll
    for (int i = 0; i < 4; ++i)
#pragma unroll
      for (int jf = 0; jf < 4; ++jf)
        acc[i][jf] = __builtin_amdgcn_mfma_f32_16x16x32_f16(af[i], bf[jf], acc[i][jf], 0, 0, 0);
  }
  int fq = lane >> 4;
#pragma unroll
  for (int i = 0; i < 4; ++i)
#pragma unroll
    for (int jf = 0; jf < 4; ++jf) {
      int col = wc * 64 + jf * 16 + fr;
      float bv = bias[col];
#pragma unroll
      for (int e = 0; e < 4; ++e) {
        int row = wr * 64 + i * 16 + fq * 4 + e;
        C[(long)row * 1024 + col] = acc[i][jf][e] + bv;
      }
    }
}

// ---------------------------------------------------------------------------
// Encoder v5: 256 blocks = d(2) x bg(8; 16 rows) x cg(16; 16 hcols), 256 thr.
// Depth-4 sentinel ring. Step t: poll slot t&3 for h_t (non-SENT data = flag);
// re-arm slot (t+2)&3 (holds h_{t-2}, provably consumed: siblings produced h_t);
// vmcnt(0); store h_{t+1} into slot (t+1)&3. Release chain: SENT completes
// before h_{t+1} issues, and a sibling polls slot (t+2)&3 only after consuming
// h_{t+1} -> it can never observe stale h_{t-2}. No flags, 2 barriers/step.
__global__ __launch_bounds__(256, 1) void encoder_k(
    const u16* __restrict__ wencf, const float* __restrict__ xp,
    u32* hglob,
    float* h0b, float* h1b, float* cfb, float* cbb) {
  int b = blockIdx.x;
  int g16 = ((b >> 7) << 3) | (b & 7);        // group (d,bg)
  int cg = (b >> 3) & 15;
  int d = g16 >> 3, bg = g16 & 7;
  int tid = threadIdx.x, lane = tid & 63, wid = tid >> 6;   // wid = gate g
  int r_t = tid >> 4, cc = tid & 15;          // epilogue cell (batch row, hcol)

  __shared__ __align__(16) char hlds[8192];   // h_t [16 r][256 k f16], XOR-swizzled
  __shared__ float red[4 * 16 * 20];          // [g][n-col][20 pad]

  f16x8 bfrag[8];                             // W_hh B-frags: 32 VGPRs, static idx
  {
    const u16* wp = wencf + ((long)(d * 16 + cg) * 4 + wid) * 4096 + lane * 8;
#pragma unroll
    for (int ks = 0; ks < 8; ++ks)
      bfrag[ks] = __builtin_bit_cast(f16x8, *(const u16x8*)&wp[ks * 512]);
  }
#pragma unroll
  for (int q = 0; q < 4; ++q)
    *(u64*)(hlds + tid * 8 + q * 2048) = 0ull;   // h_0 = 0

  float c_state = 0.f;
  long xpbase = ((long)(d * 512) * 128 + bg * 16 + r_t) * 1024 + cg * 16 + cc;
  float xpv[4];
#pragma unroll
  for (int g = 0; g < 4; ++g) xpv[g] = xp[xpbase + g * 256];

  u64* hg = (u64*)hglob;                      // [16 g][4 slot][16 r][64 u64]
  int r2 = tid >> 4, jj = tid & 15;
  long gbase0 = (long)g16 * 4096 + r2 * 64 + jj * 4;               // + slot*1024
  long mybase = (long)g16 * 4096 + r_t * 64 + cg * 4 + (cc >> 2);  // storer addr
  int lbase = r2 * 512 + jj * 32, lxor = (r2 & 7) << 4;
  __syncthreads();

  for (int t = 0; t < 512; ++t) {
    if (t != 0) {
      // --- poll+gather h_t from slot t&3 ---
      long gb = gbase0 + (long)(t & 3) * 1024;
      u64 v0 = SENT, v1 = SENT, v2 = SENT, v3 = SENT;
      for (;;) {
        bool ok = true;
        if (v0 == SENT) { v0 = ald64(hg + gb + 0); ok &= (v0 != SENT); }
        if (v1 == SENT) { v1 = ald64(hg + gb + 1); ok &= (v1 != SENT); }
        if (v2 == SENT) { v2 = ald64(hg + gb + 2); ok &= (v2 != SENT); }
        if (v3 == SENT) { v3 = ald64(hg + gb + 3); ok &= (v3 != SENT); }
        if (ok) break;
      }
      // re-arm my words in the h_{t+2} slot (holds consumed h_{t-2})
      if ((cc & 3) == 0)
        ast64(hg + mybase + (long)((t + 2) & 3) * 1024, SENT);
      // gathered h_t -> LDS (swizzled)
      *(u64*)(hlds + ((lbase +  0) ^ lxor)) = v0;
      *(u64*)(hlds + ((lbase +  8) ^ lxor)) = v1;
      *(u64*)(hlds + ((lbase + 16) ^ lxor)) = v2;
      *(u64*)(hlds + ((lbase + 24) ^ lxor)) = v3;
    }
    __syncthreads();

    // --- MFMA: gate partials = h_t @ Whh_slice^T ---
    f32x4 acc = {};
    if (t != 0) {
      int abase = (lane & 15) * 512 + (lane >> 4) * 16;
      int axor = (lane & 7) << 4;
#pragma unroll
      for (int ks = 0; ks < 8; ++ks) {
        f16x8 af = *(const f16x8*)(hlds + ((abase + ks * 64) ^ axor));
        acc = __builtin_amdgcn_mfma_f32_16x16x32_f16(af, bfrag[ks], acc, 0, 0, 0);
      }
    }
    *(f32x4*)&red[(wid * 16 + (lane & 15)) * 20 + (lane >> 4) * 4] = acc;
    __syncthreads();

    // --- epilogue: thread (r_t, cc) ---
    float gv[4];
#pragma unroll
    for (int g = 0; g < 4; ++g) gv[g] = red[(g * 16 + cc) * 20 + r_t] + xpv[g];
    float iv = 1.f / (1.f + expf(-gv[0]));
    float fv = 1.f / (1.f + expf(-gv[1]));
    float gt = tanhf(gv[2]);
    float ov = 1.f / (1.f + expf(-gv[3]));
    c_state = fv * c_state + iv * gt;
    float hval = ov * tanhf(c_state);

    if (t < 511) {
      u16 hb = f2h(hval);
      int ph = __shfl_xor((int)hb, 1);
      u32 pk = (u32)hb | (((u32)ph & 0xffffu) << 16);   // cols (cc,cc+1) at even cc
      u32 hi = (u32)__shfl_xor((int)pk, 2);             // cols (cc+2,cc+3)
      // release: SENT re-arm (and everything else) completes before data store
      asm volatile("s_waitcnt vmcnt(0)" ::: "memory");
      if ((cc & 3) == 0) {
        u64 v = (u64)pk | ((u64)hi << 32);
        ast64(hg + mybase + (long)((t + 1) & 3) * 1024, v);   // fire h_{t+1}, no wait
      }
      // prefetch next xp while stores/polls fly
      long xb2 = xpbase + (long)(t + 1) * 131072;
#pragma unroll
      for (int g = 0; g < 4; ++g) xpv[g] = xp[xb2 + g * 256];
    } else {
      int rowg = bg * 16 + r_t, colg = cg * 16 + cc;
      (d ? h1b : h0b)[32768 + rowg * 256 + colg] = hval;  // parity-1 slot for decoder
      (d ? cbb : cfb)[rowg * 256 + colg] = c_state;
    }
  }
}

// ---------------------------------------------------------------------------
// Decoder (R2, proven): 256 blocks = L(2) x bg(16) x jg(8), 512 thr.
__global__ __launch_bounds__(512) void decoder_k(
    const u32* __restrict__ dwf16, const float* __restrict__ dbias,
    float* h0b, float* h1b, float* inpb,
    const float* __restrict__ cfb, const float* __restrict__ cbb,
    float* hist, int* df) {
  int bid = blockIdx.x;
  int L = bid >> 7, bg = (bid >> 3) & 15, jg = bid & 7;
  int tid = threadIdx.x;
  int j = tid & 31, ks = tid >> 5;

  u32 w2[4][16];
  {
    const u32* p = dwf16 + (long)(L * 16 + ks) * 16384 + jg * 32 + j;
#pragma unroll
    for (int kp = 0; kp < 16; ++kp)
#pragma unroll
      for (int g = 0; g < 4; ++g)
        w2[g][kp] = p[(kp * 4 + g) * 256];
  }

  __shared__ u32 xl[8][256];
  __shared__ float red[16][8][4][32];
  float c_state = 0.f;
  if (tid < 256)
    c_state = (L ? cbb : cfb)[(bg * 8 + (tid >> 5)) * 256 + jg * 32 + (tid & 31)];
  int srow = tid >> 6, sk8 = (tid & 63) * 8;

  for (int t = 0; t < 64; ++t) {
    if (tid < 16) {
      int p = tid & 7, which = tid >> 3;
      int need = (which == 0) ? ((L == 0) ? t : t + 1) : t;
      int* fp = &df[which * 128 + bg * 8 + p];
      while (__hip_atomic_load(fp, __ATOMIC_RELAXED, __HIP_MEMORY_SCOPE_AGENT) < need)
        __builtin_amdgcn_s_sleep(1);
    }
    __syncthreads();
    {
      const float* xsrc  = (L == 0) ? inpb + (t & 1) * 32768 : h0b + (t & 1) * 32768;
      const float* hsrc2 = (L == 0) ? h0b + ((t + 1) & 1) * 32768 : h1b + ((t + 1) & 1) * 32768;
      const float* s = (sk8 < 256) ? &xsrc[(bg * 8 + srow) * 256 + sk8]
                                   : &hsrc2[(bg * 8 + srow) * 256 + sk8 - 256];
      u32 pk[4];
#pragma unroll
      for (int q = 0; q < 4; ++q) {
        float v0 = __hip_atomic_load(&s[2 * q],     __ATOMIC_RELAXED, __HIP_MEMORY_SCOPE_AGENT);
        float v1 = __hip_atomic_load(&s[2 * q + 1], __ATOMIC_RELAXED, __HIP_MEMORY_SCOPE_AGENT);
        pk[q] = packf16(v0, v1);
      }
      *(u32x4*)&xl[srow][(tid & 63) * 4] = (u32x4){pk[0], pk[1], pk[2], pk[3]};
    }
    __syncthreads();

    float acc[8][4] = {};
#pragma unroll
    for (int r = 0; r < 8; ++r) {
#pragma unroll
      for (int kc = 0; kc < 4; ++kc) {
        const u32* hq = &xl[r][ks * 16 + kc * 4];
        u32 q0 = hq[0], q1 = hq[1], q2 = hq[2], q3 = hq[3];
#pragma unroll
        for (int g = 0; g < 4; ++g) {
          acc[r][g] = dot2(q0, w2[g][kc * 4 + 0], acc[r][g]);
          acc[r][g] = dot2(q1, w2[g][kc * 4 + 1], acc[r][g]);
          acc[r][g] = dot2(q2, w2[g][kc * 4 + 2], acc[r][g]);
          acc[r][g] = dot2(q3, w2[g][kc * 4 + 3], acc[r][g]);
        }
      }
    }
#pragma unroll
    for (int r = 0; r < 8; ++r)
#pragma unroll
      for (int g = 0; g < 4; ++g)
        red[ks][r][g][j] = acc[r][g];
    __syncthreads();

    if (tid < 256) {
      int re = tid >> 5, je = tid & 31;
      float gv[4];
#pragma unroll
      for (int g = 0; g < 4; ++g) {
        float sum = dbias[L * 1024 + g * 256 + jg * 32 + je];
#pragma unroll
        for (int p = 0; p < 16; ++p) sum += red[p][re][g][je];
        gv[g] = sum;
      }
      float iv = 1.f / (1.f + expf(-gv[0]));
      float fv = 1.f / (1.f + expf(-gv[1]));
      float gt = tanhf(gv[2]);
      float ov = 1.f / (1.f + expf(-gv[3]));
      c_state = fv * c_state + iv * gt;
      float hval = ov * tanhf(c_state);
      int rowg = bg * 8 + re, colg = jg * 32 + je;
      if (L == 0) {
        __hip_atomic_store(&h0b[(t & 1) * 32768 + rowg * 256 + colg], hval,
                           __ATOMIC_RELAXED, __HIP_MEMORY_SCOPE_AGENT);
      } else {
        __hip_atomic_store(&h1b[(t & 1) * 32768 + rowg * 256 + colg], hval,
                           __ATOMIC_RELAXED, __HIP_MEMORY_SCOPE_AGENT);
        __hip_atomic_store(&inpb[((t + 1) & 1) * 32768 + rowg * 256 + colg], hval,
                           __ATOMIC_RELAXED, __HIP_MEMORY_SCOPE_AGENT);
        hist[((long)t * 128 + rowg) * 256 + colg] = hval;
      }
    }
    asm volatile("s_waitcnt vmcnt(0)" ::: "memory");
    __syncthreads();
    if (tid == 0)
      __hip_atomic_store(&df[L * 128 + bg * 8 + jg], t + 1,
                         __ATOMIC_RELAXED, __HIP_MEMORY_SCOPE_AGENT);
  }
}

// ---------------------------------------------------------------------------
__global__ __launch_bounds__(256) void logits_k(
    const float* __restrict__ hist, const float* __restrict__ lw,
    const float* __restrict__ lb, float* __restrict__ out) {
  int widx = threadIdx.x >> 6, lane = threadIdx.x & 63;
  int row = blockIdx.x * 4 + widx;
  const float* h = hist + (long)row * 256;
  float4 hv = *(const float4*)&h[lane * 4];
  float s[3];
#pragma unroll
  for (int v = 0; v < 3; ++v) {
    float4 wv = *(const float4*)&lw[v * 256 + lane * 4];
    float p = hv.x * wv.x + hv.y * wv.y + hv.z * wv.z + hv.w * wv.w;
#pragma unroll
    for (int o = 32; o > 0; o >>= 1) p += __shfl_xor(p, o, 64);
    s[v] = p;
  }
  if (lane == 0) {
    out[row * 3 + 0] = s[0] + lb[0];
    out[row * 3 + 1] = s[1] + lb[1];
    out[row * 3 + 2] = s[2] + lb[2];
  }
}

// ---------------------------------------------------------------------------
extern "C" void kernel_launch(void* const* d_in, const int* in_sizes, int n_in,
                              void* d_out, int out_size, void* d_ws, size_t ws_size,
                              hipStream_t stream) {
  const float* x     = (const float*)d_in[0];
  const float* ewihf = (const float*)d_in[1];
  const float* ewhhf = (const float*)d_in[2];
  const float* ebihf = (const float*)d_in[3];
  const float* ebhhf = (const float*)d_in[4];
  const float* ewihb = (const float*)d_in[5];
  const float* ewhhb = (const float*)d_in[6];
  const float* ebihb = (const float*)d_in[7];
  const float* ebhhb = (const float*)d_in[8];
  const float* dwih0 = (const float*)d_in[9];
  const float* dwhh0 = (const float*)d_in[10];
  const float* dbih0 = (const float*)d_in[11];
  const float* dbhh0 = (const float*)d_in[12];
  const float* dwih1 = (const float*)d_in[13];
  const float* dwhh1 = (const float*)d_in[14];
  const float* dbih1 = (const float*)d_in[15];
  const float* dbhh1 = (const float*)d_in[16];
  const float* lw    = (const float*)d_in[17];
  const float* lb    = (const float*)d_in[18];
  float* out = (float*)d_out;
  (void)in_sizes; (void)n_in; (void)out_size; (void)ws_size;

  char* wsb = (char*)d_ws;
  size_t off = 0;
  auto take = [&](size_t bytes) -> char* {
    char* p = wsb + off;
    off = (off + bytes + 255) & ~(size_t)255;
    return p;
  };
  u16*   xh    = (u16*)take(67108864ull * 2);    // x f16
  u16*   whx   = (u16*)take(2097152ull * 2);     // ew_ih f,b f16
  float* xp    = (float*)take(134217728ull * 4); // Xproj [2][512][128][1024] fp32
  u16*   wencf = (u16*)take(524288ull * 2);      // enc W_hh MFMA frags
  u32*   dwf16 = (u32*)take(524288ull * 4);      // dec weights f16 pairs
  float* bias2 = (float*)take(2048 * 4);
  float* dbias = (float*)take(2048 * 4);
  u32*   hglob = (u32*)take(131072ull * 4);      // enc h ring [16g][4 slot][16r][128]
  float* h0b   = (float*)take(65536 * 4);
  float* h1b   = (float*)take(65536 * 4);
  float* inpb  = (float*)take(65536 * 4);
  float* cfb   = (float*)take(32768 * 4);
  float* cbb   = (float*)take(32768 * 4);
  float* hist  = (float*)take(2097152 * 4);
  int*   df    = (int*)take(256 * 4);

  init_k<<<512, 256, 0, stream>>>(inpb, hglob, df);
  convert_k<<<2048, 256, 0, stream>>>(x, ewihf, ewihb, ebihf, ebhhf, ebihb, ebhhb,
                                      dbih0, dbhh0, dbih1, dbhh1, xh, whx, bias2, dbias);
  convert_we_k<<<2048, 256, 0, stream>>>(ewhhf, ewhhb, wencf);
  convert_wd_k<<<2048, 256, 0, stream>>>(dwih0, dwhh0, dwih1, dwhh1, dwf16);
  xproj_gemm<<<8192, 256, 0, stream>>>(xh, whx, bias2, xp);
  encoder_k<<<256, 256, 0, stream>>>(wencf, xp, hglob, h0b, h1b, cfb, cbb);
  decoder_k<<<256, 512, 0, stream>>>(dwf16, dbias, h0b, h1b, inpb, cfb, cbb, hist, df);
  logits_k<<<2048, 256, 0, stream>>>(hist, lw, lb, out);
}